// Round 3
// baseline (345.942 us; speedup 1.0000x reference)
//
#include <hip/hip_runtime.h>
#include <hip/hip_bf16.h>

typedef __attribute__((ext_vector_type(8)))  __bf16 bf16x8;
typedef __attribute__((ext_vector_type(16))) float  f32x16;

#define SDIM 49
#define NDIM 1024
#define CDIM 384
#define DDIM 512
#define DMC  64
#define NROWS (2*NDIM)
#define SCALE (1.0f/(SDIM*NDIM))

__device__ __forceinline__ void gload16(const void* g, void* l) {
    __builtin_amdgcn_global_load_lds((const __attribute__((address_space(1))) void*)g,
                                     (__attribute__((address_space(3))) void*)l, 16, 0, 0);
}

// ---------------------------------------------------------------------------
// pack + fused passthrough copy.
// pack: x [N,C,S] (f32) + m [N,64] + c [N,64] -> bf16 [S, N, 512] row-major.
// copy: block j also copies x[j] (C*S floats) to the output slab (L2 re-read).
// ---------------------------------------------------------------------------
__global__ __launch_bounds__(512) void pack_copy_kernel(
    const float* __restrict__ xloc, const float* __restrict__ mv,
    const float* __restrict__ cv,   __hip_bfloat16* __restrict__ dst,
    float* __restrict__ cpy)
{
    const int j = blockIdx.x;
    const int d = threadIdx.x;
    float vals[SDIM];
    if (d < CDIM) {
        const float* p = xloc + ((size_t)j * CDIM + d) * SDIM;
        #pragma unroll
        for (int s = 0; s < SDIM; ++s) vals[s] = p[s];
    } else if (d < CDIM + DMC) {
        float v = mv[j * DMC + (d - CDIM)];
        #pragma unroll
        for (int s = 0; s < SDIM; ++s) vals[s] = v;
    } else {
        float v = cv[j * DMC + (d - CDIM - DMC)];
        #pragma unroll
        for (int s = 0; s < SDIM; ++s) vals[s] = v;
    }
    #pragma unroll
    for (int s = 0; s < SDIM; ++s)
        dst[((size_t)s * NDIM + j) * DDIM + d] = __float2bfloat16(vals[s]);

    // passthrough copy of this sample's slab (reads hit L2)
    const float* src = xloc + (size_t)j * CDIM * SDIM;
    float* dcp = cpy + (size_t)j * CDIM * SDIM;
    for (int i = threadIdx.x; i < CDIM * SDIM; i += 512) dcp[i] = src[i];
}

__global__ void fpack_kernel(const float* __restrict__ f,
                             __hip_bfloat16* __restrict__ dst, int n)
{
    int i = blockIdx.x * blockDim.x + threadIdx.x;
    if (i < n) dst[i] = __float2bfloat16(f[i]);
}

// ---------------------------------------------------------------------------
// Tile GEMM + partial-LSE epilogue.
// grid = 49 s * 16 rowblocks * 8 colblocks = 6272 blocks of 256 (4 waves).
// Block: 128 q-rows x 128 keys, full D=512 via 8 dc-iters of 64.
// LDS 32KB: Q[64 ldsrows][256B] @0, K @16K. Global row g -> (lr=g&63, h=g>>6),
// byte o in [0,128): addr = lr*256 + ((h*128+o) ^ ((lr&15)<<4)).  Staging uses
// linear LDS dest + pre-swizzled global source (same bijection).
// Wave tile 32 rows x 128 keys: per kk 1 A-read + 4 B-reads + 4 MFMA.
// MFMA 32x32x16 bf16, C/D: col=lane&31, row=(reg&3)+8*(reg>>2)+4*(lane>>5).
// Epilogue: per-row (max, sum-exp) partial -> part[s*2048+row][cb]; diag
// blocks atomicAdd -sum(diag) directly.
// ---------------------------------------------------------------------------
__global__ __launch_bounds__(256, 4) void loss_kernel(
    const __hip_bfloat16* __restrict__ Fm,   // [N,512]
    const __hip_bfloat16* __restrict__ Km,   // [S,N,512] keys
    const __hip_bfloat16* __restrict__ Qm,   // [S,N,512] queries (pred2)
    float2* __restrict__ part,
    float* __restrict__ out)
{
    __shared__ __attribute__((aligned(16))) char sm[32768];

    const int bid = blockIdx.x;
    const int gid = (bid & 7) * 784 + (bid >> 3);   // XCD-chunked, bijective
    const int s   = gid >> 7;
    const int rem = gid & 127;
    const int rb  = rem >> 3;
    const int cb  = rem & 7;

    const int tid  = threadIdx.x;
    const int lane = tid & 63;
    const int w    = tid >> 6;
    const int r31  = lane & 31;
    const int hi   = lane >> 5;

    const char* Qg = (rb < 8)
        ? ((const char*)Fm + (size_t)rb * 128 * 1024)
        : ((const char*)Qm + ((size_t)s * NDIM + (size_t)(rb - 8) * 128) * 1024);
    const char* Kg = (const char*)Km + ((size_t)s * NDIM + (size_t)cb * 128) * 1024;

    // staging constants (linear LDS dest, pre-swizzled source)
    const int sp  = (tid & 15) ^ (tid >> 4);
    const int hst = sp >> 3;
    const int ost = (sp & 7) << 4;
    const char* qsrc = Qg + (size_t)((tid >> 4) + hst * 64) * 1024 + ost;
    const char* ksrc = Kg + (size_t)((tid >> 4) + hst * 64) * 1024 + ost;
    char* qdst = sm + tid * 16;
    char* kdst = sm + 16384 + tid * 16;

    auto stage = [&](int dc) {
        const int dco = dc * 128;
        #pragma unroll
        for (int rnd = 0; rnd < 4; ++rnd) {
            gload16(qsrc + rnd * 16384 + dco, qdst + rnd * 4096);
            gload16(ksrc + rnd * 16384 + dco, kdst + rnd * 4096);
        }
    };

    const unsigned swz    = (unsigned)((r31 & 15) << 4);
    const unsigned abase  = (unsigned)(((w & 1) * 32 + r31) * 256);
    const unsigned hqo    = (unsigned)((w >> 1) * 128);
    const unsigned b0base = 16384u + (unsigned)(r31 * 256);
    const unsigned b1base = 16384u + (unsigned)((32 + r31) * 256);

    f32x16 acc0{}, acc1{}, acc2{}, acc3{};

    stage(0);
    for (int dc = 0; dc < 8; ++dc) {
        asm volatile("s_waitcnt vmcnt(0)" ::: "memory");
        __syncthreads();
        #pragma unroll
        for (int kk = 0; kk < 4; ++kk) {
            const unsigned kb8 = (unsigned)(kk * 32 + hi * 16);
            bf16x8 a  = *(const bf16x8*)(sm + abase  + ((hqo + kb8) ^ swz));
            bf16x8 b0 = *(const bf16x8*)(sm + b0base + (kb8 ^ swz));
            bf16x8 b1 = *(const bf16x8*)(sm + b1base + (kb8 ^ swz));
            bf16x8 b2 = *(const bf16x8*)(sm + b0base + ((128u + kb8) ^ swz));
            bf16x8 b3 = *(const bf16x8*)(sm + b1base + ((128u + kb8) ^ swz));
            acc0 = __builtin_amdgcn_mfma_f32_32x32x16_bf16(a, b0, acc0, 0, 0, 0);
            acc1 = __builtin_amdgcn_mfma_f32_32x32x16_bf16(a, b1, acc1, 0, 0, 0);
            acc2 = __builtin_amdgcn_mfma_f32_32x32x16_bf16(a, b2, acc2, 0, 0, 0);
            acc3 = __builtin_amdgcn_mfma_f32_32x32x16_bf16(a, b3, acc3, 0, 0, 0);
        }
        __syncthreads();
        if (dc < 7) stage(dc + 1);
    }

    // ---- partial LSE epilogue: per-row (m, sum) over this block's 128 keys
    float lm[16], ls[16];
    #pragma unroll
    for (int r = 0; r < 16; ++r) {
        float v0 = acc0[r], v1 = acc1[r], v2 = acc2[r], v3 = acc3[r];
        float m = fmaxf(fmaxf(v0, v1), fmaxf(v2, v3));
        lm[r] = m;
        ls[r] = __expf(v0 - m) + __expf(v1 - m) + __expf(v2 - m) + __expf(v3 - m);
    }
    #pragma unroll
    for (int off = 1; off < 32; off <<= 1) {
        #pragma unroll
        for (int r = 0; r < 16; ++r) {
            float mo = __shfl_xor(lm[r], off, 64);
            float so = __shfl_xor(ls[r], off, 64);
            float d  = lm[r] - mo;
            float e  = __expf(-fabsf(d));
            ls[r] = (d >= 0.0f) ? (ls[r] + so * e) : (so + ls[r] * e);
            lm[r] = fmaxf(lm[r], mo);
        }
    }
    if (r31 == 0) {
        const size_t rowbase = (size_t)s * NROWS + (size_t)rb * 128 + w * 32;
        #pragma unroll
        for (int r = 0; r < 16; ++r) {
            const int row = (r & 3) + 8 * (r >> 2) + 4 * hi;
            part[(rowbase + row) * 8 + cb] = make_float2(lm[r], ls[r]);
        }
    }

    // ---- diagonal extraction (blocks on the diagonal only)
    if (cb == (rb & 7)) {
        float dsum = 0.0f;
        #pragma unroll
        for (int r = 0; r < 16; ++r) {
            const int row = (r & 3) + 8 * (r >> 2) + 4 * hi;
            float v = (w == 0) ? acc0[r] : (w == 1) ? acc1[r]
                    : (w == 2) ? acc2[r] : acc3[r];
            if (r31 == row) dsum += v;
        }
        #pragma unroll
        for (int off = 1; off < 64; off <<= 1) dsum += __shfl_xor(dsum, off, 64);
        float* red = (float*)sm;               // sm free after final barrier
        if (lane == 0) red[w] = dsum;
        __syncthreads();
        if (tid == 0)
            atomicAdd(out, -(red[0] + red[1] + red[2] + red[3]) * SCALE);
    }
}

// merge the 8 per-colblock partials of each row -> lse, accumulate loss
__global__ __launch_bounds__(256) void reduce_kernel(
    const float2* __restrict__ part, float* __restrict__ out)
{
    const int row = blockIdx.x * 256 + threadIdx.x;   // 392*256 = 100352 rows
    const float2* p = part + (size_t)row * 8;
    float m = -3.0e38f, ssum = 0.0f;
    #pragma unroll
    for (int i = 0; i < 8; ++i) {
        float2 q = p[i];
        float d = m - q.x;
        float e = __expf(-fabsf(d));
        ssum = (d >= 0.0f) ? (ssum + q.y * e) : (q.y + ssum * e);
        m = fmaxf(m, q.x);
    }
    float v = m + __logf(ssum);
    #pragma unroll
    for (int off = 1; off < 64; off <<= 1) v += __shfl_xor(v, off, 64);
    __shared__ float red[4];
    const int lane = threadIdx.x & 63, w = threadIdx.x >> 6;
    if (lane == 0) red[w] = v;
    __syncthreads();
    if (threadIdx.x == 0)
        atomicAdd(out, (red[0] + red[1] + red[2] + red[3]) * SCALE);
}

extern "C" void kernel_launch(void* const* d_in, const int* in_sizes, int n_in,
                              void* d_out, int out_size, void* d_ws, size_t ws_size,
                              hipStream_t stream)
{
    (void)in_sizes; (void)n_in; (void)out_size; (void)ws_size;
    const float* f  = (const float*)d_in[0];
    const float* x  = (const float*)d_in[1];
    const float* xp = (const float*)d_in[2];
    const float* mt = (const float*)d_in[3];
    const float* mp = (const float*)d_in[4];
    const float* ct = (const float*)d_in[5];
    const float* cp = (const float*)d_in[6];
    float* out = (float*)d_out;

    char* ws = (char*)d_ws;
    const size_t packBytes = (size_t)SDIM * NDIM * DDIM * 2;   // 51.4 MB
    __hip_bfloat16* Km = (__hip_bfloat16*)ws;
    __hip_bfloat16* Qm = (__hip_bfloat16*)(ws + packBytes);
    __hip_bfloat16* Fm = (__hip_bfloat16*)(ws + 2 * packBytes);
    float2* part = (float2*)(ws + 2 * packBytes + (size_t)NDIM * DDIM * 2);

    hipMemsetAsync(out, 0, sizeof(float), stream);

    const int sz = NDIM * CDIM * SDIM;
    pack_copy_kernel<<<NDIM, 512, 0, stream>>>(xp, mp, cp, Km, out + 1);
    pack_copy_kernel<<<NDIM, 512, 0, stream>>>(x,  mt, ct, Qm, out + 1 + sz);
    fpack_kernel<<<(NDIM * DDIM + 255) / 256, 256, 0, stream>>>(f, Fm, NDIM * DDIM);

    loss_kernel<<<6272, 256, 0, stream>>>(Fm, Km, Qm, part, out);
    reduce_kernel<<<392, 256, 0, stream>>>(part, out);
}

// Round 4
// 269.118 us; speedup vs baseline: 1.2855x; 1.2855x over previous
//
#include <hip/hip_runtime.h>
#include <hip/hip_bf16.h>

typedef __attribute__((ext_vector_type(8)))  __bf16 bf16x8;
typedef __attribute__((ext_vector_type(16))) float  f32x16;

#define SDIM 49
#define NDIM 1024
#define CDIM 384
#define DDIM 512
#define DMC  64
#define SCALE (1.0f/(SDIM*NDIM))
#define RINGSZ 24576   // Q 16KB + K 8KB per ring slot; 4 slots = 96KB

__device__ __forceinline__ void gload16(const void* g, void* l) {
    __builtin_amdgcn_global_load_lds((const __attribute__((address_space(1))) void*)g,
                                     (__attribute__((address_space(3))) void*)l, 16, 0, 0);
}

// ---------------------------------------------------------------------------
// pack + fused passthrough copy (same as R3, validated).
// ---------------------------------------------------------------------------
__global__ __launch_bounds__(512) void pack_copy_kernel(
    const float* __restrict__ xloc, const float* __restrict__ mv,
    const float* __restrict__ cv,   __hip_bfloat16* __restrict__ dst,
    float* __restrict__ cpy)
{
    const int j = blockIdx.x;
    const int d = threadIdx.x;
    float vals[SDIM];
    if (d < CDIM) {
        const float* p = xloc + ((size_t)j * CDIM + d) * SDIM;
        #pragma unroll
        for (int s = 0; s < SDIM; ++s) vals[s] = p[s];
    } else if (d < CDIM + DMC) {
        float v = mv[j * DMC + (d - CDIM)];
        #pragma unroll
        for (int s = 0; s < SDIM; ++s) vals[s] = v;
    } else {
        float v = cv[j * DMC + (d - CDIM - DMC)];
        #pragma unroll
        for (int s = 0; s < SDIM; ++s) vals[s] = v;
    }
    #pragma unroll
    for (int s = 0; s < SDIM; ++s)
        dst[((size_t)s * NDIM + j) * DDIM + d] = __float2bfloat16(vals[s]);

    const float* src = xloc + (size_t)j * CDIM * SDIM;
    float* dcp = cpy + (size_t)j * CDIM * SDIM;
    for (int i = threadIdx.x; i < CDIM * SDIM; i += 512) dcp[i] = src[i];
}

__global__ void fpack_kernel(const float* __restrict__ f,
                             __hip_bfloat16* __restrict__ dst, int n)
{
    int i = blockIdx.x * blockDim.x + threadIdx.x;
    if (i < n) dst[i] = __float2bfloat16(f[i]);
}

// ---------------------------------------------------------------------------
// Fused GEMM + partial-LSE, 4-deep ring pipeline with counted vmcnt.
// grid = 49 s * 8 qblk * 8 kblk = 3136 blocks of 512 (8 waves: wq[0..4) x wkey[0..2)).
// Block tile: 256 q-rows x 128 keys, K-step BK=32 (16 iters over D=512).
// SWAPPED operands: D[key, q] = mfma(A=K_frag, B=Q_frag) so each lane holds
// one q-row (col=r31) with 32 key-values in-register per acc pair -> in-lane
// partial LSE (no shuffle tree).
// LDS ring slot: Q 256 rows x 64B @0 (row g: lr=g&63, sub=g>>6), K 128 rows
// x 64B @16384 (lr=g&31, sub=g>>5); addr = lr*256 + ((sub*64+o)^((lr&15)<<4)).
// Staging: linear LDS dest + pre-swizzled global source (same bijection).
// Pipeline: issue stage(t+3); vmcnt(9) [drains ring t only]; barrier;
// compute ring t; barrier.  Tail: vmcnt(6/3/0).  Raw s_barrier (NOT
// __syncthreads) so the compiler does not insert a vmcnt(0) drain.
// MFMA 32x32x16 bf16, C/D: col=lane&31, row=(reg&3)+8*(reg>>2)+4*(lane>>5).
// ---------------------------------------------------------------------------
__global__ __launch_bounds__(512, 2) void loss_kernel(
    const __hip_bfloat16* __restrict__ Fm,   // [N,512]
    const __hip_bfloat16* __restrict__ Km,   // [S,N,512] keys
    const __hip_bfloat16* __restrict__ Qm,   // [S,N,512] queries (pred2)
    float2* __restrict__ part,               // [S*2048][16]
    float* __restrict__ out)
{
    extern __shared__ __attribute__((aligned(16))) char sm[];   // 4*RINGSZ

    const int bid = blockIdx.x;
    const int gid = (bid & 7) * 392 + (bid >> 3);   // XCD-chunked, bijective
    const int s    = gid >> 6;
    const int rem  = gid & 63;
    const int qblk = rem >> 3;
    const int kblk = rem & 7;

    const int tid  = threadIdx.x;
    const int lane = tid & 63;
    const int w    = tid >> 6;          // 0..7
    const int r31  = lane & 31;
    const int hi   = lane >> 5;
    const int wq   = w >> 1;            // 0..3  (64-q chunk)
    const int wkey = w & 1;             // 0..1  (64-key chunk)

    const char* Qg = (qblk < 4)
        ? ((const char*)Fm + (size_t)qblk * 256 * 1024)
        : ((const char*)Qm + ((size_t)s * NDIM + (size_t)(qblk - 4) * 256) * 1024);
    const char* Kg = (const char*)Km + ((size_t)s * NDIM + (size_t)kblk * 128) * 1024;

    // ---- staging constants (linear dest, pre-swizzled source)
    const int sp = (tid & 15) ^ ((tid >> 4) & 15);
    const size_t qrow0 = (size_t)((tid >> 4) + 64 * (sp >> 2)) * 1024 + ((sp & 3) << 4);
    const size_t qrow1 = qrow0 + (size_t)32 * 1024;
    const size_t krow  = (size_t)((tid >> 4) + 32 * (sp >> 2)) * 1024 + ((sp & 3) << 4);

    #define STAGE(T) do {                                                   \
        char* rb_ = sm + (size_t)((T) & 3) * RINGSZ;                        \
        const size_t dcol_ = (size_t)(T) * 64;                              \
        gload16(Qg + qrow0 + dcol_, rb_ + tid * 16);                        \
        gload16(Qg + qrow1 + dcol_, rb_ + 8192 + tid * 16);                 \
        gload16(Kg + krow  + dcol_, rb_ + 16384 + tid * 16);                \
    } while (0)

    // ---- compute constants
    const unsigned swz   = (unsigned)((r31 & 15) << 4);
    const unsigned aoff  = 16384u + (unsigned)r31 * 256u;      // K: lr=r31 for both ka
    const unsigned boff0 = (unsigned)r31 * 256u;               // Q qb=0: lr=r31
    const unsigned boff1 = (unsigned)(32 + r31) * 256u;        // Q qb=1
    const unsigned subA0 = (unsigned)(wkey * 2) * 64u;         // K sub = wkey*2+ka
    const unsigned subB  = (unsigned)wq * 64u;                 // Q sub = wq

    f32x16 acc00{}, acc01{}, acc10{}, acc11{};

    #define COMPUTE(T) do {                                                          \
        const char* rb_ = sm + (size_t)((T) & 3) * RINGSZ;                           \
        _Pragma("unroll")                                                            \
        for (int kk = 0; kk < 2; ++kk) {                                             \
            const unsigned ko_ = (unsigned)(kk * 32 + hi * 16);                      \
            bf16x8 a0 = *(const bf16x8*)(rb_ + aoff  + ((subA0 + ko_) ^ swz));       \
            bf16x8 a1 = *(const bf16x8*)(rb_ + aoff  + ((subA0 + 64u + ko_) ^ swz)); \
            bf16x8 b0 = *(const bf16x8*)(rb_ + boff0 + ((subB + ko_) ^ swz));        \
            bf16x8 b1 = *(const bf16x8*)(rb_ + boff1 + ((subB + ko_) ^ swz));        \
            acc00 = __builtin_amdgcn_mfma_f32_32x32x16_bf16(a0, b0, acc00, 0, 0, 0); \
            acc01 = __builtin_amdgcn_mfma_f32_32x32x16_bf16(a0, b1, acc01, 0, 0, 0); \
            acc10 = __builtin_amdgcn_mfma_f32_32x32x16_bf16(a1, b0, acc10, 0, 0, 0); \
            acc11 = __builtin_amdgcn_mfma_f32_32x32x16_bf16(a1, b1, acc11, 0, 0, 0); \
        }                                                                            \
    } while (0)

    // ---- prologue: 3 rings in flight (9 loads)
    STAGE(0); STAGE(1); STAGE(2);

    // ---- main loop: counted vmcnt, never 0
    for (int t = 0; t < 13; ++t) {
        STAGE(t + 3);
        asm volatile("s_waitcnt vmcnt(9)" ::: "memory");   // ring t complete
        __builtin_amdgcn_s_barrier();
        __builtin_amdgcn_s_setprio(1);
        COMPUTE(t);
        __builtin_amdgcn_s_setprio(0);
        asm volatile("" ::: "memory");
        __builtin_amdgcn_s_barrier();
    }
    // ---- tail: t = 13,14,15
    asm volatile("s_waitcnt vmcnt(6)" ::: "memory");
    __builtin_amdgcn_s_barrier();
    COMPUTE(13);
    asm volatile("" ::: "memory");
    __builtin_amdgcn_s_barrier();
    asm volatile("s_waitcnt vmcnt(3)" ::: "memory");
    __builtin_amdgcn_s_barrier();
    COMPUTE(14);
    asm volatile("" ::: "memory");
    __builtin_amdgcn_s_barrier();
    asm volatile("s_waitcnt vmcnt(0)" ::: "memory");
    __builtin_amdgcn_s_barrier();
    COMPUTE(15);

    // ---- epilogue: in-lane partial LSE per q-row over this wave's 64 keys
    // lane (r31,hi) / acc[ka][qb][r]: q = wq*64+qb*32+r31,
    // key = kblk*128 + wkey*64 + ka*32 + (r&3)+8*(r>>2)+4*hi
    float m0 = -3.0e38f, m1 = -3.0e38f;
    #pragma unroll
    for (int r = 0; r < 16; ++r) {
        m0 = fmaxf(m0, fmaxf(acc00[r], acc10[r]));
        m1 = fmaxf(m1, fmaxf(acc01[r], acc11[r]));
    }
    float s0 = 0.0f, s1 = 0.0f;
    #pragma unroll
    for (int r = 0; r < 16; ++r) {
        s0 += __expf(acc00[r] - m0) + __expf(acc10[r] - m0);
        s1 += __expf(acc01[r] - m1) + __expf(acc11[r] - m1);
    }
    // merge hi halves (keys interleave across hi)
    {
        float mo = __shfl_xor(m0, 32, 64), so = __shfl_xor(s0, 32, 64);
        float nm = fmaxf(m0, mo);
        s0 = s0 * __expf(m0 - nm) + so * __expf(mo - nm); m0 = nm;
        mo = __shfl_xor(m1, 32, 64); so = __shfl_xor(s1, 32, 64);
        nm = fmaxf(m1, mo);
        s1 = s1 * __expf(m1 - nm) + so * __expf(mo - nm); m1 = nm;
    }
    {
        const float mm = hi ? m1 : m0;
        const float ss = hi ? s1 : s0;
        const int row_local = wq * 64 + hi * 32 + r31;
        const size_t row = (size_t)s * 2048 + (size_t)qblk * 256 + row_local;
        part[row * 16 + kblk * 2 + wkey] = make_float2(mm, ss);
    }

    // ---- diagonal: q_global_in_set == key_global
    // block has diag iff kblk>>1 == (qblk&3); then q_local = (kblk&1)*128 + k_local
    if ((kblk >> 1) == (qblk & 3) && wq == ((kblk & 1) * 2 + wkey)) {
        const int regd = (r31 & 3) | ((r31 >> 3) << 2);
        float d = 0.0f;
        if (hi == ((r31 >> 2) & 1)) {
            #pragma unroll
            for (int r = 0; r < 16; ++r)
                if (r == regd) d = acc00[r] + acc11[r];
        }
        #pragma unroll
        for (int off = 1; off < 64; off <<= 1) d += __shfl_xor(d, off, 64);
        if (lane == 0) atomicAdd(out, -d * SCALE);
    }
    #undef STAGE
    #undef COMPUTE
}

// merge the 16 per-(kblk,wkey) partials of each row -> lse, accumulate loss
__global__ __launch_bounds__(256) void reduce_kernel(
    const float2* __restrict__ part, float* __restrict__ out)
{
    const int row = blockIdx.x * 256 + threadIdx.x;   // 392*256 = 100352 rows
    const float2* p = part + (size_t)row * 16;
    float m = -3.0e38f;
    float2 q[16];
    #pragma unroll
    for (int i = 0; i < 16; ++i) { q[i] = p[i]; m = fmaxf(m, q[i].x); }
    float ssum = 0.0f;
    #pragma unroll
    for (int i = 0; i < 16; ++i) ssum += q[i].y * __expf(q[i].x - m);
    float v = m + __logf(ssum);
    #pragma unroll
    for (int off = 1; off < 64; off <<= 1) v += __shfl_xor(v, off, 64);
    __shared__ float red[4];
    const int lane = threadIdx.x & 63, w = threadIdx.x >> 6;
    if (lane == 0) red[w] = v;
    __syncthreads();
    if (threadIdx.x == 0)
        atomicAdd(out, (red[0] + red[1] + red[2] + red[3]) * SCALE);
}

extern "C" void kernel_launch(void* const* d_in, const int* in_sizes, int n_in,
                              void* d_out, int out_size, void* d_ws, size_t ws_size,
                              hipStream_t stream)
{
    (void)in_sizes; (void)n_in; (void)out_size; (void)ws_size;
    const float* f  = (const float*)d_in[0];
    const float* x  = (const float*)d_in[1];
    const float* xp = (const float*)d_in[2];
    const float* mt = (const float*)d_in[3];
    const float* mp = (const float*)d_in[4];
    const float* ct = (const float*)d_in[5];
    const float* cp = (const float*)d_in[6];
    float* out = (float*)d_out;

    char* ws = (char*)d_ws;
    const size_t packBytes = (size_t)SDIM * NDIM * DDIM * 2;   // 51.4 MB
    __hip_bfloat16* Km = (__hip_bfloat16*)ws;
    __hip_bfloat16* Qm = (__hip_bfloat16*)(ws + packBytes);
    __hip_bfloat16* Fm = (__hip_bfloat16*)(ws + 2 * packBytes);
    float2* part = (float2*)(ws + 2 * packBytes + (size_t)NDIM * DDIM * 2);

    hipMemsetAsync(out, 0, sizeof(float), stream);

    const int sz = NDIM * CDIM * SDIM;
    pack_copy_kernel<<<NDIM, 512, 0, stream>>>(xp, mp, cp, Km, out + 1);
    pack_copy_kernel<<<NDIM, 512, 0, stream>>>(x,  mt, ct, Qm, out + 1 + sz);
    fpack_kernel<<<(NDIM * DDIM + 255) / 256, 256, 0, stream>>>(f, Fm, NDIM * DDIM);

    loss_kernel<<<3136, 512, 4 * RINGSZ, stream>>>(Fm, Km, Qm, part, out);
    reduce_kernel<<<392, 256, 0, stream>>>(part, out);
}

// Round 6
// 255.759 us; speedup vs baseline: 1.3526x; 1.0522x over previous
//
#include <hip/hip_runtime.h>
#include <hip/hip_bf16.h>

typedef __attribute__((ext_vector_type(8))) __bf16 bf16x8;
typedef __attribute__((ext_vector_type(4))) float  f32x4;

#define SDIM 49
#define NDIM 1024
#define CDIM 384
#define DDIM 512
#define DMC  64
#define SCALE (1.0f/(SDIM*NDIM))
#define SLOT 65536   // A(keys) 32KB + B(q) 32KB per K-step slot; 2 slots = 128KB

__device__ __forceinline__ void gload16(const void* g, void* l) {
    __builtin_amdgcn_global_load_lds((const __attribute__((address_space(1))) void*)g,
                                     (__attribute__((address_space(3))) void*)l, 16, 0, 0);
}

// ---------------------------------------------------------------------------
// pack + fused passthrough copy (validated R3/R4).
// ---------------------------------------------------------------------------
__global__ __launch_bounds__(512) void pack_copy_kernel(
    const float* __restrict__ xloc, const float* __restrict__ mv,
    const float* __restrict__ cv,   __hip_bfloat16* __restrict__ dst,
    float* __restrict__ cpy)
{
    const int j = blockIdx.x;
    const int d = threadIdx.x;
    float vals[SDIM];
    if (d < CDIM) {
        const float* p = xloc + ((size_t)j * CDIM + d) * SDIM;
        #pragma unroll
        for (int s = 0; s < SDIM; ++s) vals[s] = p[s];
    } else if (d < CDIM + DMC) {
        float v = mv[j * DMC + (d - CDIM)];
        #pragma unroll
        for (int s = 0; s < SDIM; ++s) vals[s] = v;
    } else {
        float v = cv[j * DMC + (d - CDIM - DMC)];
        #pragma unroll
        for (int s = 0; s < SDIM; ++s) vals[s] = v;
    }
    #pragma unroll
    for (int s = 0; s < SDIM; ++s)
        dst[((size_t)s * NDIM + j) * DDIM + d] = __float2bfloat16(vals[s]);

    const float* src = xloc + (size_t)j * CDIM * SDIM;
    float* dcp = cpy + (size_t)j * CDIM * SDIM;
    for (int i = threadIdx.x; i < CDIM * SDIM; i += 512) dcp[i] = src[i];
}

__global__ void fpack_kernel(const float* __restrict__ f,
                             __hip_bfloat16* __restrict__ dst, int n)
{
    int i = blockIdx.x * blockDim.x + threadIdx.x;
    if (i < n) dst[i] = __float2bfloat16(f[i]);
}

// ---------------------------------------------------------------------------
// Fused GEMM + partial-LSE, m201-class geometry on R4's counted-vmcnt ring.
// grid = 49 s * 4 kb * 8 qb = 1568 blocks of 512 (8 waves = 2 wk x 4 wq).
// GEMM view (swapped): M = keys (A from Km), N = q-rows (B from Fm/Qm), K=D.
// Block tile 256 keys x 256 q, BK=64 (8 K-steps); wave tile 128 keys x 64 q.
// MFMA 16x16x32 bf16: acc[a=0..7][b=0..3] f32x4; C/D col=lane&15,
// row=(lane>>4)*4+reg.  Per K-step/wave: 24 ds_read_b128 : 64 MFMA.
// LDS slot: A rows [256][128B] @0, B rows [256][128B] @32K;
// content[row][col] = G[row][kstep*128 + (col ^ ((row&7)<<4))]; staged with
// linear LDS dest + pre-swizzled global source.
// Pipeline: STAGE(t+1); vmcnt(8) [slot t complete]; barrier; compute; barrier.
// part slots per q-row: kb(4) x wk(2) = 8  (R5 bug: wk was missing -> race).
// ---------------------------------------------------------------------------
__global__ __launch_bounds__(512, 2) void loss_kernel(
    const __hip_bfloat16* __restrict__ Fm,   // [N,512]
    const __hip_bfloat16* __restrict__ Km,   // [S,N,512] keys
    const __hip_bfloat16* __restrict__ Qm,   // [S,N,512] queries (pred2)
    float2* __restrict__ part,               // [S*2048][8]
    float* __restrict__ out)
{
    extern __shared__ __attribute__((aligned(16))) char sm[];   // 2*SLOT

    const int bid = blockIdx.x;
    const int gid = (bid & 7) * 196 + (bid >> 3);   // XCD-chunked, bijective
    const int s   = gid >> 5;
    const int rem = gid & 31;
    const int kb  = rem >> 3;     // key block (0..3)
    const int qb  = rem & 7;      // q block  (0..7): 0-3 = Fm, 4-7 = Qm

    const int tid  = threadIdx.x;
    const int lane = tid & 63;
    const int w    = tid >> 6;
    const int l15  = lane & 15;
    const int l4   = lane >> 4;   // 0..3
    const int wk   = w >> 2;      // 0..1 key half
    const int wq   = w & 3;       // 0..3 q quarter

    const char* Ag = (const char*)Km + ((size_t)s * NDIM + (size_t)kb * 256) * 1024;
    const char* Bg = (qb < 4)
        ? ((const char*)Fm + (size_t)qb * 256 * 1024)
        : ((const char*)Qm + ((size_t)s * NDIM + (size_t)(qb - 4) * 256) * 1024);

    // staging: thread covers rows c*64 + (tid>>3), 16B col (tid&7)*16;
    // pre-swizzled source col = col ^ ((row&7)<<4)  (lane-constant xor)
    const int trow = tid >> 3;
    const int scol = (((tid & 7) ^ ((tid >> 3) & 7)) << 4);

    #define STAGE(T) do {                                                     \
        char* sb_ = sm + (size_t)((T) & 1) * SLOT;                            \
        const size_t ko_ = (size_t)(T) * 128;                                 \
        _Pragma("unroll")                                                     \
        for (int c = 0; c < 4; ++c) {                                         \
            gload16(Ag + (size_t)(c * 64 + trow) * 1024 + ko_ + scol,         \
                    sb_ + c * 8192 + tid * 16);                               \
            gload16(Bg + (size_t)(c * 64 + trow) * 1024 + ko_ + scol,         \
                    sb_ + 32768 + c * 8192 + tid * 16);                       \
        }                                                                     \
    } while (0)

    // compute-side addressing
    const unsigned xo   = (unsigned)((l15 & 7) << 4);
    const unsigned arow = (unsigned)((wk * 128 + l15) * 128);
    const unsigned brow = 32768u + (unsigned)((wq * 64 + l15) * 128);

    f32x4 acc[8][4];
    #pragma unroll
    for (int a = 0; a < 8; ++a)
        #pragma unroll
        for (int b = 0; b < 4; ++b) acc[a][b] = f32x4{0.f, 0.f, 0.f, 0.f};

    #define COMPUTE(T) do {                                                   \
        const char* sb_ = sm + (size_t)((T) & 1) * SLOT;                      \
        _Pragma("unroll")                                                     \
        for (int kc = 0; kc < 2; ++kc) {                                      \
            const unsigned col = ((unsigned)(kc * 64 + l4 * 16)) ^ xo;        \
            bf16x8 bfr[4], afr[8];                                            \
            _Pragma("unroll")                                                 \
            for (int b = 0; b < 4; ++b)                                       \
                bfr[b] = *(const bf16x8*)(sb_ + brow + b * 2048 + col);       \
            _Pragma("unroll")                                                 \
            for (int a = 0; a < 8; ++a)                                       \
                afr[a] = *(const bf16x8*)(sb_ + arow + a * 2048 + col);       \
            _Pragma("unroll")                                                 \
            for (int a = 0; a < 8; ++a)                                       \
                _Pragma("unroll")                                             \
                for (int b = 0; b < 4; ++b)                                   \
                    acc[a][b] = __builtin_amdgcn_mfma_f32_16x16x32_bf16(      \
                        afr[a], bfr[b], acc[a][b], 0, 0, 0);                  \
        }                                                                     \
    } while (0)

    STAGE(0);
    for (int t = 0; t < 8; ++t) {
        if (t < 7) {
            STAGE(t + 1);
            asm volatile("s_waitcnt vmcnt(8)" ::: "memory");   // slot t ready
        } else {
            asm volatile("s_waitcnt vmcnt(0)" ::: "memory");
        }
        __builtin_amdgcn_s_barrier();
        __builtin_amdgcn_s_setprio(1);
        COMPUTE(t);
        __builtin_amdgcn_s_setprio(0);
        asm volatile("" ::: "memory");
        __builtin_amdgcn_s_barrier();
    }

    // ---- epilogue: per-lane partial LSE. Lane's q for frag-col b:
    // q = qb*256 + wq*64 + b*16 + l15; keys covered: wk*128 + a*16 + l4*4 + r,
    // merged across l4 via shuffles ^16/^32 -> 128 keys (this wave's half).
    float q_m[4], q_s[4];
    #pragma unroll
    for (int b = 0; b < 4; ++b) {
        float m = -3.0e38f;
        #pragma unroll
        for (int a = 0; a < 8; ++a)
            #pragma unroll
            for (int r = 0; r < 4; ++r) m = fmaxf(m, acc[a][b][r]);
        float ss = 0.0f;
        #pragma unroll
        for (int a = 0; a < 8; ++a)
            #pragma unroll
            for (int r = 0; r < 4; ++r) ss += __expf(acc[a][b][r] - m);
        #pragma unroll
        for (int off = 16; off <= 32; off <<= 1) {
            float mo = __shfl_xor(m, off, 64);
            float so = __shfl_xor(ss, off, 64);
            float nm = fmaxf(m, mo);
            ss = ss * __expf(m - nm) + so * __expf(mo - nm);
            m = nm;
        }
        q_m[b] = m; q_s[b] = ss;
    }
    if (lane < 16) {
        const size_t rowb = (size_t)s * 2048 + (size_t)qb * 256 + wq * 64 + lane;
        #pragma unroll
        for (int b = 0; b < 4; ++b)
            part[(rowb + b * 16) * 8 + kb * 2 + wk] = make_float2(q_m[b], q_s[b]);
    }

    // ---- diagonal: q_global == key_global; block cond kb == qb&3,
    // wave cond wq>>1 == wk; frag a = (wq&1)*4 + b; lane cond l15>>2 == l4,
    // reg r = lane&3 (all compile-time indexed under the wq&1 branch).
    if (kb == (qb & 3) && (wq >> 1) == wk) {
        float d = 0.0f;
        const bool lok = (((lane >> 2) & 3) == l4);
        if (wq & 1) {
            #pragma unroll
            for (int b = 0; b < 4; ++b)
                #pragma unroll
                for (int r = 0; r < 4; ++r)
                    if (lok && r == (lane & 3)) d += acc[4 + b][b][r];
        } else {
            #pragma unroll
            for (int b = 0; b < 4; ++b)
                #pragma unroll
                for (int r = 0; r < 4; ++r)
                    if (lok && r == (lane & 3)) d += acc[b][b][r];
        }
        #pragma unroll
        for (int off = 1; off < 64; off <<= 1) d += __shfl_xor(d, off, 64);
        if (lane == 0) atomicAdd(out, -d * SCALE);
    }
    #undef STAGE
    #undef COMPUTE
}

// merge the 8 per-(kb,wk) partials of each row -> lse, accumulate loss
__global__ __launch_bounds__(256) void reduce_kernel(
    const float2* __restrict__ part, float* __restrict__ out)
{
    const int row = blockIdx.x * 256 + threadIdx.x;   // 392*256 = 100352 rows
    const float2* p = part + (size_t)row * 8;
    float m = -3.0e38f;
    float2 q[8];
    #pragma unroll
    for (int i = 0; i < 8; ++i) { q[i] = p[i]; m = fmaxf(m, q[i].x); }
    float ssum = 0.0f;
    #pragma unroll
    for (int i = 0; i < 8; ++i) ssum += q[i].y * __expf(q[i].x - m);
    float v = m + __logf(ssum);
    #pragma unroll
    for (int off = 1; off < 64; off <<= 1) v += __shfl_xor(v, off, 64);
    __shared__ float red[4];
    const int lane = threadIdx.x & 63, w = threadIdx.x >> 6;
    if (lane == 0) red[w] = v;
    __syncthreads();
    if (threadIdx.x == 0)
        atomicAdd(out, (red[0] + red[1] + red[2] + red[3]) * SCALE);
}

extern "C" void kernel_launch(void* const* d_in, const int* in_sizes, int n_in,
                              void* d_out, int out_size, void* d_ws, size_t ws_size,
                              hipStream_t stream)
{
    (void)in_sizes; (void)n_in; (void)out_size; (void)ws_size;
    const float* f  = (const float*)d_in[0];
    const float* x  = (const float*)d_in[1];
    const float* xp = (const float*)d_in[2];
    const float* mt = (const float*)d_in[3];
    const float* mp = (const float*)d_in[4];
    const float* ct = (const float*)d_in[5];
    const float* cp = (const float*)d_in[6];
    float* out = (float*)d_out;

    char* ws = (char*)d_ws;
    const size_t packBytes = (size_t)SDIM * NDIM * DDIM * 2;   // 51.4 MB
    __hip_bfloat16* Km = (__hip_bfloat16*)ws;
    __hip_bfloat16* Qm = (__hip_bfloat16*)(ws + packBytes);
    __hip_bfloat16* Fm = (__hip_bfloat16*)(ws + 2 * packBytes);
    float2* part = (float2*)(ws + 2 * packBytes + (size_t)NDIM * DDIM * 2);

    hipMemsetAsync(out, 0, sizeof(float), stream);

    const int sz = NDIM * CDIM * SDIM;
    pack_copy_kernel<<<NDIM, 512, 0, stream>>>(xp, mp, cp, Km, out + 1);
    pack_copy_kernel<<<NDIM, 512, 0, stream>>>(x,  mt, ct, Qm, out + 1 + sz);
    fpack_kernel<<<(NDIM * DDIM + 255) / 256, 256, 0, stream>>>(f, Fm, NDIM * DDIM);

    loss_kernel<<<1568, 512, 2 * SLOT, stream>>>(Fm, Km, Qm, part, out);
    reduce_kernel<<<392, 256, 0, stream>>>(part, out);
}

// Round 7
// 252.470 us; speedup vs baseline: 1.3702x; 1.0130x over previous
//
#include <hip/hip_runtime.h>
#include <hip/hip_bf16.h>

typedef __attribute__((ext_vector_type(8))) __bf16 bf16x8;
typedef __attribute__((ext_vector_type(4))) float  f32x4;

#define SDIM 49
#define NDIM 1024
#define CDIM 384
#define DDIM 512
#define DMC  64
#define SCALE (1.0f/(SDIM*NDIM))
#define SLOT 65536   // A(keys) 32KB + B(q) 32KB per K-step slot; 2 slots = 128KB

__device__ __forceinline__ void gload16(const void* g, void* l) {
    __builtin_amdgcn_global_load_lds((const __attribute__((address_space(1))) void*)g,
                                     (__attribute__((address_space(3))) void*)l, 16, 0, 0);
}

// ---------------------------------------------------------------------------
// pack + fused passthrough copy (validated R3-R6).
// ---------------------------------------------------------------------------
__global__ __launch_bounds__(512) void pack_copy_kernel(
    const float* __restrict__ xloc, const float* __restrict__ mv,
    const float* __restrict__ cv,   __hip_bfloat16* __restrict__ dst,
    float* __restrict__ cpy)
{
    const int j = blockIdx.x;
    const int d = threadIdx.x;
    float vals[SDIM];
    if (d < CDIM) {
        const float* p = xloc + ((size_t)j * CDIM + d) * SDIM;
        #pragma unroll
        for (int s = 0; s < SDIM; ++s) vals[s] = p[s];
    } else if (d < CDIM + DMC) {
        float v = mv[j * DMC + (d - CDIM)];
        #pragma unroll
        for (int s = 0; s < SDIM; ++s) vals[s] = v;
    } else {
        float v = cv[j * DMC + (d - CDIM - DMC)];
        #pragma unroll
        for (int s = 0; s < SDIM; ++s) vals[s] = v;
    }
    #pragma unroll
    for (int s = 0; s < SDIM; ++s)
        dst[((size_t)s * NDIM + j) * DDIM + d] = __float2bfloat16(vals[s]);

    const float* src = xloc + (size_t)j * CDIM * SDIM;
    float* dcp = cpy + (size_t)j * CDIM * SDIM;
    for (int i = threadIdx.x; i < CDIM * SDIM; i += 512) dcp[i] = src[i];
}

__global__ void fpack_kernel(const float* __restrict__ f,
                             __hip_bfloat16* __restrict__ dst, int n)
{
    int i = blockIdx.x * blockDim.x + threadIdx.x;
    if (i < n) dst[i] = __float2bfloat16(f[i]);
}

// ---------------------------------------------------------------------------
// Fused GEMM + partial-LSE, m201-class 8-phase schedule (4 phases/K-step).
// grid = 49 s * 4 kb * 8 qb = 1568 blocks of 512 (8 waves = 2 wk x 4 wq).
// GEMM view (swapped): M = keys (A from Km), N = q-rows (B from Fm/Qm), K=D.
// Block tile 256 keys x 256 q, BK=64 (8 K-steps); wave tile 128 keys x 64 q.
// MFMA 16x16x32 bf16: acc[a=0..7][b=0..3] f32x4; C/D col=lane&15,
// row=(lane>>4)*4+reg.
// LDS slot: A rows [256][128B] @0, B rows [256][128B] @32K;
// content[row][col] = G[row][kstep*128 + (col ^ ((row&7)<<4))]; staged with
// linear LDS dest + pre-swizzled global source (R4/R6: 0 bank conflicts).
// Phase = {ds_read subtile | stage half-tile; barrier; lgkmcnt(0);
//          setprio(1); 16 MFMA; setprio(0); barrier}.
// P1: A-half0(8)+B-half0(4) reads, stage 4; P2: B-half1(4) reads, stage 4;
// P3: A-half1(8) reads; P4: vmcnt(0) [slot t+1 loads, issued 2-3 phases ago,
// effectively counted] before barrier.  No mid-loop synchronous drain.
// ---------------------------------------------------------------------------
__global__ __launch_bounds__(512, 2) void loss_kernel(
    const __hip_bfloat16* __restrict__ Fm,   // [N,512]
    const __hip_bfloat16* __restrict__ Km,   // [S,N,512] keys
    const __hip_bfloat16* __restrict__ Qm,   // [S,N,512] queries (pred2)
    float2* __restrict__ part,               // [S*2048][8]
    float* __restrict__ out)
{
    extern __shared__ __attribute__((aligned(16))) char sm[];   // 2*SLOT

    const int bid = blockIdx.x;
    const int gid = (bid & 7) * 196 + (bid >> 3);   // XCD-chunked, bijective
    const int s   = gid >> 5;
    const int rem = gid & 31;
    const int kb  = rem >> 3;     // key block (0..3)
    const int qb  = rem & 7;      // q block  (0..7): 0-3 = Fm, 4-7 = Qm

    const int tid  = threadIdx.x;
    const int lane = tid & 63;
    const int w    = tid >> 6;
    const int l15  = lane & 15;
    const int l4   = lane >> 4;   // 0..3
    const int wk   = w >> 2;      // 0..1 key half
    const int wq   = w & 3;       // 0..3 q quarter

    const char* Ag = (const char*)Km + ((size_t)s * NDIM + (size_t)kb * 256) * 1024;
    const char* Bg = (qb < 4)
        ? ((const char*)Fm + (size_t)qb * 256 * 1024)
        : ((const char*)Qm + ((size_t)s * NDIM + (size_t)(qb - 4) * 256) * 1024);

    // staging: thread covers rows c*64 + (tid>>3), 16B col (tid&7)*16;
    // pre-swizzled source col = col ^ ((row&7)<<4)  (lane-constant xor)
    const int trow = tid >> 3;
    const int scol = (((tid & 7) ^ ((tid >> 3) & 7)) << 4);

    // stage one half (c pair) of K-step T into slot T&1: 4 gload16
    #define STAGE_HALF(T, H) do {                                             \
        char* db_ = sm + (size_t)((T) & 1) * SLOT;                            \
        const size_t ko_ = (size_t)(T) * 128;                                 \
        _Pragma("unroll")                                                     \
        for (int c = 2 * (H); c < 2 * (H) + 2; ++c) {                         \
            gload16(Ag + (size_t)(c * 64 + trow) * 1024 + ko_ + scol,         \
                    db_ + c * 8192 + tid * 16);                               \
            gload16(Bg + (size_t)(c * 64 + trow) * 1024 + ko_ + scol,         \
                    db_ + 32768 + c * 8192 + tid * 16);                       \
        }                                                                     \
    } while (0)

    // compute-side addressing
    const unsigned xo   = (unsigned)((l15 & 7) << 4);
    const unsigned arow = (unsigned)((wk * 128 + l15) * 128);
    const unsigned brow = 32768u + (unsigned)((wq * 64 + l15) * 128);

    f32x4 acc[8][4];
    #pragma unroll
    for (int a = 0; a < 8; ++a)
        #pragma unroll
        for (int b = 0; b < 4; ++b) acc[a][b] = f32x4{0.f, 0.f, 0.f, 0.f};

    bf16x8 afr[4][2], bfr[4][2];

    #define READ_A(H) do {                                                    \
        _Pragma("unroll")                                                     \
        for (int a = 0; a < 4; ++a)                                           \
            _Pragma("unroll")                                                 \
            for (int kc = 0; kc < 2; ++kc)                                    \
                afr[a][kc] = *(const bf16x8*)(sb_ + arow + (H) * 8192u        \
                    + a * 2048u + (((unsigned)(kc * 64 + l4 * 16)) ^ xo));    \
    } while (0)

    #define READ_B(H) do {                                                    \
        _Pragma("unroll")                                                     \
        for (int b = 0; b < 2; ++b)                                           \
            _Pragma("unroll")                                                 \
            for (int kc = 0; kc < 2; ++kc)                                    \
                bfr[(H)*2 + b][kc] = *(const bf16x8*)(sb_ + brow              \
                    + ((H)*2 + b) * 2048u                                     \
                    + (((unsigned)(kc * 64 + l4 * 16)) ^ xo));                \
    } while (0)

    #define MFMA_Q(AH, BH) do {                                               \
        _Pragma("unroll")                                                     \
        for (int a = 0; a < 4; ++a)                                           \
            _Pragma("unroll")                                                 \
            for (int b = 0; b < 2; ++b)                                       \
                _Pragma("unroll")                                             \
                for (int kc = 0; kc < 2; ++kc)                                \
                    acc[(AH)*4 + a][(BH)*2 + b] =                             \
                        __builtin_amdgcn_mfma_f32_16x16x32_bf16(              \
                            afr[a][kc], bfr[(BH)*2 + b][kc],                  \
                            acc[(AH)*4 + a][(BH)*2 + b], 0, 0, 0);            \
    } while (0)

    // prologue: slot 0 fully staged, drained once
    STAGE_HALF(0, 0); STAGE_HALF(0, 1);
    asm volatile("s_waitcnt vmcnt(0)" ::: "memory");
    __builtin_amdgcn_s_barrier();

    for (int t = 0; t < 8; ++t) {
        const char* sb_ = sm + (size_t)(t & 1) * SLOT;
        const bool pf = (t < 7);
        // ---- P1
        READ_A(0); READ_B(0);
        if (pf) STAGE_HALF(t + 1, 0);
        __builtin_amdgcn_s_barrier();
        asm volatile("s_waitcnt lgkmcnt(0)" ::: "memory");
        __builtin_amdgcn_s_setprio(1); MFMA_Q(0, 0); __builtin_amdgcn_s_setprio(0);
        __builtin_amdgcn_s_barrier();
        // ---- P2
        READ_B(1);
        if (pf) STAGE_HALF(t + 1, 1);
        __builtin_amdgcn_s_barrier();
        asm volatile("s_waitcnt lgkmcnt(0)" ::: "memory");
        __builtin_amdgcn_s_setprio(1); MFMA_Q(0, 1); __builtin_amdgcn_s_setprio(0);
        __builtin_amdgcn_s_barrier();
        // ---- P3
        READ_A(1);
        __builtin_amdgcn_s_barrier();
        asm volatile("s_waitcnt lgkmcnt(0)" ::: "memory");
        __builtin_amdgcn_s_setprio(1); MFMA_Q(1, 0); __builtin_amdgcn_s_setprio(0);
        __builtin_amdgcn_s_barrier();
        // ---- P4 (slot t+1 loads are 2-3 phases old -> vmcnt(0) ~free)
        asm volatile("s_waitcnt vmcnt(0)" ::: "memory");
        __builtin_amdgcn_s_barrier();
        __builtin_amdgcn_s_setprio(1); MFMA_Q(1, 1); __builtin_amdgcn_s_setprio(0);
        __builtin_amdgcn_s_barrier();
    }

    // ---- epilogue: per-lane partial LSE. Lane's q for frag-col b:
    // q = qb*256 + wq*64 + b*16 + l15; keys covered: wk*128 + a*16 + l4*4 + r,
    // merged across l4 via shuffles ^16/^32 -> 128 keys (this wave's half).
    float q_m[4], q_s[4];
    #pragma unroll
    for (int b = 0; b < 4; ++b) {
        float m = -3.0e38f;
        #pragma unroll
        for (int a = 0; a < 8; ++a)
            #pragma unroll
            for (int r = 0; r < 4; ++r) m = fmaxf(m, acc[a][b][r]);
        float ss = 0.0f;
        #pragma unroll
        for (int a = 0; a < 8; ++a)
            #pragma unroll
            for (int r = 0; r < 4; ++r) ss += __expf(acc[a][b][r] - m);
        #pragma unroll
        for (int off = 16; off <= 32; off <<= 1) {
            float mo = __shfl_xor(m, off, 64);
            float so = __shfl_xor(ss, off, 64);
            float nm = fmaxf(m, mo);
            ss = ss * __expf(m - nm) + so * __expf(mo - nm);
            m = nm;
        }
        q_m[b] = m; q_s[b] = ss;
    }
    if (lane < 16) {
        const size_t rowb = (size_t)s * 2048 + (size_t)qb * 256 + wq * 64 + lane;
        #pragma unroll
        for (int b = 0; b < 4; ++b)
            part[(rowb + b * 16) * 8 + kb * 2 + wk] = make_float2(q_m[b], q_s[b]);
    }

    // ---- diagonal: q_global == key_global; block cond kb == qb&3,
    // wave cond wq>>1 == wk; frag a = (wq&1)*4 + b; lane cond l15>>2 == l4,
    // reg r = lane&3 (all compile-time indexed under the wq&1 branch).
    if (kb == (qb & 3) && (wq >> 1) == wk) {
        float d = 0.0f;
        const bool lok = (((lane >> 2) & 3) == l4);
        if (wq & 1) {
            #pragma unroll
            for (int b = 0; b < 4; ++b)
                #pragma unroll
                for (int r = 0; r < 4; ++r)
                    if (lok && r == (lane & 3)) d += acc[4 + b][b][r];
        } else {
            #pragma unroll
            for (int b = 0; b < 4; ++b)
                #pragma unroll
                for (int r = 0; r < 4; ++r)
                    if (lok && r == (lane & 3)) d += acc[b][b][r];
        }
        #pragma unroll
        for (int off = 1; off < 64; off <<= 1) d += __shfl_xor(d, off, 64);
        if (lane == 0) atomicAdd(out, -d * SCALE);
    }
    #undef STAGE_HALF
    #undef READ_A
    #undef READ_B
    #undef MFMA_Q
}

// merge the 8 per-(kb,wk) partials of each row -> lse, accumulate loss
__global__ __launch_bounds__(256) void reduce_kernel(
    const float2* __restrict__ part, float* __restrict__ out)
{
    const int row = blockIdx.x * 256 + threadIdx.x;   // 392*256 = 100352 rows
    const float2* p = part + (size_t)row * 8;
    float m = -3.0e38f;
    float2 q[8];
    #pragma unroll
    for (int i = 0; i < 8; ++i) { q[i] = p[i]; m = fmaxf(m, q[i].x); }
    float ssum = 0.0f;
    #pragma unroll
    for (int i = 0; i < 8; ++i) ssum += q[i].y * __expf(q[i].x - m);
    float v = m + __logf(ssum);
    #pragma unroll
    for (int off = 1; off < 64; off <<= 1) v += __shfl_xor(v, off, 64);
    __shared__ float red[4];
    const int lane = threadIdx.x & 63, w = threadIdx.x >> 6;
    if (lane == 0) red[w] = v;
    __syncthreads();
    if (threadIdx.x == 0)
        atomicAdd(out, (red[0] + red[1] + red[2] + red[3]) * SCALE);
}

extern "C" void kernel_launch(void* const* d_in, const int* in_sizes, int n_in,
                              void* d_out, int out_size, void* d_ws, size_t ws_size,
                              hipStream_t stream)
{
    (void)in_sizes; (void)n_in; (void)out_size; (void)ws_size;
    const float* f  = (const float*)d_in[0];
    const float* x  = (const float*)d_in[1];
    const float* xp = (const float*)d_in[2];
    const float* mt = (const float*)d_in[3];
    const float* mp = (const float*)d_in[4];
    const float* ct = (const float*)d_in[5];
    const float* cp = (const float*)d_in[6];
    float* out = (float*)d_out;

    char* ws = (char*)d_ws;
    const size_t packBytes = (size_t)SDIM * NDIM * DDIM * 2;   // 51.4 MB
    __hip_bfloat16* Km = (__hip_bfloat16*)ws;
    __hip_bfloat16* Qm = (__hip_bfloat16*)(ws + packBytes);
    __hip_bfloat16* Fm = (__hip_bfloat16*)(ws + 2 * packBytes);
    float2* part = (float2*)(ws + 2 * packBytes + (size_t)NDIM * DDIM * 2);

    hipMemsetAsync(out, 0, sizeof(float), stream);

    const int sz = NDIM * CDIM * SDIM;
    pack_copy_kernel<<<NDIM, 512, 0, stream>>>(xp, mp, cp, Km, out + 1);
    pack_copy_kernel<<<NDIM, 512, 0, stream>>>(x,  mt, ct, Qm, out + 1 + sz);
    fpack_kernel<<<(NDIM * DDIM + 255) / 256, 256, 0, stream>>>(f, Fm, NDIM * DDIM);

    loss_kernel<<<1568, 512, 2 * SLOT, stream>>>(Fm, Km, Qm, part, out);
    reduce_kernel<<<392, 256, 0, stream>>>(part, out);
}